// Round 9
// baseline (197.899 us; speedup 1.0000x reference)
//
#include <hip/hip_runtime.h>

#define N_NODES 100000
#define M_EDGES 1600000
#define CH 64
#define NPB 128                              // nodes per bucket (col >> 7)
#define NB ((N_NODES + NPB - 1) / NPB)       // 782 buckets
#define PART_CHUNK 8192
#define PART_BLOCKS ((M_EDGES + PART_CHUNK - 1) / PART_CHUNK)  // 196
#define REG_E 12                             // 256 thr * 12 = 3072 bucket cap (mean 2046, +22 sigma)
#define GROWS 192                            // gemm rows per block
#define GBLKS ((N_NODES + GROWS - 1) / GROWS)  // 521

// f32 -> bf16 (RNE) pack of two channels into one uint
__device__ __forceinline__ unsigned int pack_bf16x2(float a, float b) {
    unsigned int ua = __float_as_uint(a);
    ua = (ua + 0x7fffu + ((ua >> 16) & 1u)) >> 16;
    unsigned int ub = __float_as_uint(b);
    ub = (ub + 0x7fffu + ((ub >> 16) & 1u)) >> 16;
    return ua | (ub << 16);
}
__device__ __forceinline__ float bf_lo(unsigned int u) { return __uint_as_float(u << 16); }
__device__ __forceinline__ float bf_hi(unsigned int u) { return __uint_as_float(u & 0xffff0000u); }

// ---------- bucket histogram: per-chunk 782-bin hist -> table T[chunk][bucket] ----------
__global__ __launch_bounds__(256) void k_bhist(const int* __restrict__ col, int* __restrict__ T) {
    __shared__ int h[NB];
    int tid = threadIdx.x;
    for (int i = tid; i < NB; i += 256) h[i] = 0;
    __syncthreads();
    const int4* c4 = (const int4*)col;
    int start4 = blockIdx.x * (PART_CHUNK / 4);
    int end4 = min(M_EDGES / 4, start4 + PART_CHUNK / 4);
    for (int e = start4 + tid; e < end4; e += 256) {
        int4 v = c4[e];
        atomicAdd(&h[v.x >> 7], 1);
        atomicAdd(&h[v.y >> 7], 1);
        atomicAdd(&h[v.z >> 7], 1);
        atomicAdd(&h[v.w >> 7], 1);
    }
    __syncthreads();
    for (int i = tid; i < NB; i += 256) T[blockIdx.x * NB + i] = h[i];
}

// ---------- fused column-sum + exclusive scan: T -> bbase (+sentinel), bcur ----------
// thread b sums column b over 196 chunk-rows (coalesced across threads), then LDS scan.
__global__ __launch_bounds__(1024) void k_sumscan(const int* __restrict__ T, int* __restrict__ bbase,
                                                  int* __restrict__ bcur) {
    __shared__ int s[1024];
    int t = threadIdx.x;
    int sum = 0;
    if (t < NB) {
#pragma unroll 4
        for (int c = 0; c < PART_BLOCKS; c++) sum += T[c * NB + t];
    }
    s[t] = sum;
    __syncthreads();
    for (int off = 1; off < 1024; off <<= 1) {
        int tv = (t >= off) ? s[t - off] : 0;
        __syncthreads();
        s[t] += tv;
        __syncthreads();
    }
    if (t < NB) {
        int e = s[t] - sum;  // exclusive
        bbase[t] = e;
        bcur[t] = e;
    }
    if (t == NB - 1) bbase[NB] = s[t];  // sentinel = M
}

// ---------- coarse partition: claim per-block sub-ranges from bcur, then scatter ----------
__global__ __launch_bounds__(256) void k_partition(const int* __restrict__ row, const int* __restrict__ col,
                                                   int* __restrict__ bcur, const int* __restrict__ T,
                                                   unsigned int* __restrict__ pairs) {
    __shared__ int h[NB];
    int tid = threadIdx.x;
    int c = blockIdx.x;
    for (int i = tid; i < NB; i += 256) {
        int cnt = T[c * NB + i];
        h[i] = cnt ? atomicAdd(&bcur[i], cnt) : 0;  // claim contiguous sub-range within bucket
    }
    __syncthreads();
    const int4* c4 = (const int4*)col;
    const int4* r4 = (const int4*)row;
    int start4 = c * (PART_CHUNK / 4);
    int end4 = min(M_EDGES / 4, start4 + PART_CHUNK / 4);
    for (int e = start4 + tid; e < end4; e += 256) {
        int4 cc = c4[e];
        int4 rr = r4[e];
        int pos;
        pos = atomicAdd(&h[cc.x >> 7], 1);
        pairs[pos] = ((unsigned int)rr.x << 7) | (unsigned int)(cc.x & 127);
        pos = atomicAdd(&h[cc.y >> 7], 1);
        pairs[pos] = ((unsigned int)rr.y << 7) | (unsigned int)(cc.y & 127);
        pos = atomicAdd(&h[cc.z >> 7], 1);
        pairs[pos] = ((unsigned int)rr.z << 7) | (unsigned int)(cc.z & 127);
        pos = atomicAdd(&h[cc.w >> 7], 1);
        pairs[pos] = ((unsigned int)rr.w << 7) | (unsigned int)(cc.w & 127);
    }
}

// ---------- in-place per-bucket counting sort; emits nstart (+sentinel) and dis ----------
__global__ __launch_bounds__(256) void k_fine(const int* __restrict__ bbase,
                                              unsigned int* __restrict__ pairs, int* __restrict__ node_start,
                                              float* __restrict__ dis) {
    __shared__ int lcnt[NPB];
    __shared__ int lcur[NPB];
    __shared__ int ss[NPB];
    int b = blockIdx.x, t = threadIdx.x;
    int s0 = bbase[b], e0 = bbase[b + 1];

    if (t < NPB) lcnt[t] = 0;
    __syncthreads();

    unsigned int reg[REG_E];  // compile-time indexed only (rule #20)
#pragma unroll
    for (int k = 0; k < REG_E; k++) {
        int e = s0 + t + k * 256;
        if (e < e0) {
            unsigned int p = pairs[e];
            reg[k] = p;
            atomicAdd(&lcnt[p & 127u], 1);
        }
    }
    __syncthreads();

    int v = 0;
    if (t < NPB) { v = lcnt[t]; ss[t] = v; }
    __syncthreads();
    for (int off = 1; off < NPB; off <<= 1) {
        int tv = (t < NPB && t >= off) ? ss[t - off] : 0;
        __syncthreads();
        if (t < NPB) ss[t] += tv;
        __syncthreads();
    }
    if (t < NPB) {
        int excl = ss[t] - v;
        lcur[t] = excl;
        int node = b * NPB + t;
        if (node < N_NODES) {
            node_start[node] = s0 + excl;
            dis[node] = 1.0f / sqrtf((float)(v + 1));  // degree incl. self-loop
        }
        if (b == NB - 1 && t == 0) node_start[N_NODES] = e0;  // sentinel
    }
    __syncthreads();

#pragma unroll
    for (int k = 0; k < REG_E; k++) {
        int e = s0 + t + k * 256;
        if (e < e0) {
            unsigned int p = reg[k];
            int pos = atomicAdd(&lcur[p & 127u], 1);
            pairs[s0 + pos] = p >> 7;  // rows grouped by target node
        }
    }
}

// ---------- g = dis[r] * (x @ W), packed bf16; wave = 16-col quad, lane = row, 3 rows/thread ----------
__global__ __launch_bounds__(256) void k_gemm_g(const float* __restrict__ x, const float* __restrict__ W,
                                                const float* __restrict__ dis, unsigned int* __restrict__ g2) {
    __shared__ float sW[64][64];
    __shared__ float sXf[GROWS * 65];  // [row][k] with +1 pad
    int t = threadIdx.x;
    int row0 = blockIdx.x * GROWS;
    int nrows = min(GROWS, N_NODES - row0);

    for (int i = t; i < 64 * 64; i += 256) sW[i >> 6][i & 63] = W[i];
    const float4* xv = (const float4*)x;
    for (int idx = t; idx < GROWS * 16; idx += 256) {
        int r = idx >> 4, c4 = idx & 15;
        float4 v = (r < nrows) ? xv[(size_t)(row0 + r) * 16 + c4] : make_float4(0.f, 0.f, 0.f, 0.f);
        sXf[r * 65 + c4 * 4 + 0] = v.x;
        sXf[r * 65 + c4 * 4 + 1] = v.y;
        sXf[r * 65 + c4 * 4 + 2] = v.z;
        sXf[r * 65 + c4 * 4 + 3] = v.w;
    }
    __syncthreads();

    int q = t >> 6;          // wave id -> col quad
    int rid = t & 63;        // lane -> row
    int c0 = q * 16;
    float acc0[16], acc1[16], acc2[16];
#pragma unroll
    for (int j = 0; j < 16; j++) { acc0[j] = 0.f; acc1[j] = 0.f; acc2[j] = 0.f; }

    for (int k = 0; k < 64; k++) {
        float xv0 = sXf[rid * 65 + k];
        float xv1 = sXf[(rid + 64) * 65 + k];
        float xv2 = sXf[(rid + 128) * 65 + k];
        const float4* wp = (const float4*)&sW[k][c0];  // same addr across wave: broadcast
        float4 w0 = wp[0], w1 = wp[1], w2 = wp[2], w3 = wp[3];
        float wv[16] = {w0.x, w0.y, w0.z, w0.w, w1.x, w1.y, w1.z, w1.w,
                        w2.x, w2.y, w2.z, w2.w, w3.x, w3.y, w3.z, w3.w};
#pragma unroll
        for (int j = 0; j < 16; j++) {
            acc0[j] += xv0 * wv[j];
            acc1[j] += xv1 * wv[j];
            acc2[j] += xv2 * wv[j];
        }
    }

#pragma unroll
    for (int jr = 0; jr < 3; jr++) {
        int r = rid + jr * 64;
        int gr = row0 + r;
        if (r < nrows) {
            float* accp = (jr == 0) ? acc0 : (jr == 1) ? acc1 : acc2;  // unrolled: compile-time
            float d = dis[gr];
            uint4 wlo, whi;
            wlo.x = pack_bf16x2(d * accp[0], d * accp[1]);
            wlo.y = pack_bf16x2(d * accp[2], d * accp[3]);
            wlo.z = pack_bf16x2(d * accp[4], d * accp[5]);
            wlo.w = pack_bf16x2(d * accp[6], d * accp[7]);
            whi.x = pack_bf16x2(d * accp[8], d * accp[9]);
            whi.y = pack_bf16x2(d * accp[10], d * accp[11]);
            whi.z = pack_bf16x2(d * accp[12], d * accp[13]);
            whi.w = pack_bf16x2(d * accp[14], d * accp[15]);
            unsigned int base = (unsigned int)gr * 32 + q * 8;
            *reinterpret_cast<uint4*>(&g2[base]) = wlo;
            *reinterpret_cast<uint4*>(&g2[base + 4]) = whi;
        }
    }
}

// ---------- aggregation: 2 nodes/wave, 8 lanes/edge (uint4 = 8 ch), 32 edges/node/iter MLP=8 ----------
// out[c] = dis[c] * (sum_e g[srow_e] + g[c]) + b
__global__ __launch_bounds__(256) void k_aggregate(const int* __restrict__ nstart, const int* __restrict__ srow,
                                                   const float* __restrict__ dis, const unsigned int* __restrict__ g2,
                                                   const float* __restrict__ bias, float* __restrict__ out) {
    int node = blockIdx.x * 8 + (threadIdx.x >> 5);   // 32 lanes per node; grid*8 == N exactly
    if (node >= N_NODES) return;
    int l = threadIdx.x & 31;
    int grp = l >> 3;   // edge slot 0..3
    int sub = l & 7;    // channel octet: channels 8*sub .. 8*sub+7
    const uint4* gq = (const uint4*)g2;  // one g-row = 8 uint4
    int s0 = nstart[node];
    int e0 = nstart[node + 1];
    // issue self-loop row + dis early so they join the first latency round
    uint4 su = gq[(unsigned int)node * 8 + sub];
    float d = dis[node];
    float a0 = 0.f, a1 = 0.f, a2 = 0.f, a3 = 0.f, a4 = 0.f, a5 = 0.f, a6 = 0.f, a7 = 0.f;
    int e0m1 = e0 - 1;
    for (int i = s0; i < e0; i += 32) {  // masked 32-wide iters, 8 gathers in flight
        int ea0 = i + grp,      ea1 = i + 4 + grp,  ea2 = i + 8 + grp,  ea3 = i + 12 + grp;
        int ea4 = i + 16 + grp, ea5 = i + 20 + grp, ea6 = i + 24 + grp, ea7 = i + 28 + grp;
        int r0 = srow[min(ea0, e0m1)];
        int r1 = srow[min(ea1, e0m1)];
        int r2 = srow[min(ea2, e0m1)];
        int r3 = srow[min(ea3, e0m1)];
        int r4 = srow[min(ea4, e0m1)];
        int r5 = srow[min(ea5, e0m1)];
        int r6 = srow[min(ea6, e0m1)];
        int r7 = srow[min(ea7, e0m1)];
        uint4 u0 = gq[(unsigned int)r0 * 8 + sub];
        uint4 u1 = gq[(unsigned int)r1 * 8 + sub];
        uint4 u2 = gq[(unsigned int)r2 * 8 + sub];
        uint4 u3 = gq[(unsigned int)r3 * 8 + sub];
        uint4 u4 = gq[(unsigned int)r4 * 8 + sub];
        uint4 u5 = gq[(unsigned int)r5 * 8 + sub];
        uint4 u6 = gq[(unsigned int)r6 * 8 + sub];
        uint4 u7 = gq[(unsigned int)r7 * 8 + sub];
        if (ea0 < e0) { a0 += bf_lo(u0.x); a1 += bf_hi(u0.x); a2 += bf_lo(u0.y); a3 += bf_hi(u0.y);
                        a4 += bf_lo(u0.z); a5 += bf_hi(u0.z); a6 += bf_lo(u0.w); a7 += bf_hi(u0.w); }
        if (ea1 < e0) { a0 += bf_lo(u1.x); a1 += bf_hi(u1.x); a2 += bf_lo(u1.y); a3 += bf_hi(u1.y);
                        a4 += bf_lo(u1.z); a5 += bf_hi(u1.z); a6 += bf_lo(u1.w); a7 += bf_hi(u1.w); }
        if (ea2 < e0) { a0 += bf_lo(u2.x); a1 += bf_hi(u2.x); a2 += bf_lo(u2.y); a3 += bf_hi(u2.y);
                        a4 += bf_lo(u2.z); a5 += bf_hi(u2.z); a6 += bf_lo(u2.w); a7 += bf_hi(u2.w); }
        if (ea3 < e0) { a0 += bf_lo(u3.x); a1 += bf_hi(u3.x); a2 += bf_lo(u3.y); a3 += bf_hi(u3.y);
                        a4 += bf_lo(u3.z); a5 += bf_hi(u3.z); a6 += bf_lo(u3.w); a7 += bf_hi(u3.w); }
        if (ea4 < e0) { a0 += bf_lo(u4.x); a1 += bf_hi(u4.x); a2 += bf_lo(u4.y); a3 += bf_hi(u4.y);
                        a4 += bf_lo(u4.z); a5 += bf_hi(u4.z); a6 += bf_lo(u4.w); a7 += bf_hi(u4.w); }
        if (ea5 < e0) { a0 += bf_lo(u5.x); a1 += bf_hi(u5.x); a2 += bf_lo(u5.y); a3 += bf_hi(u5.y);
                        a4 += bf_lo(u5.z); a5 += bf_hi(u5.z); a6 += bf_lo(u5.w); a7 += bf_hi(u5.w); }
        if (ea6 < e0) { a0 += bf_lo(u6.x); a1 += bf_hi(u6.x); a2 += bf_lo(u6.y); a3 += bf_hi(u6.y);
                        a4 += bf_lo(u6.z); a5 += bf_hi(u6.z); a6 += bf_lo(u6.w); a7 += bf_hi(u6.w); }
        if (ea7 < e0) { a0 += bf_lo(u7.x); a1 += bf_hi(u7.x); a2 += bf_lo(u7.y); a3 += bf_hi(u7.y);
                        a4 += bf_lo(u7.z); a5 += bf_hi(u7.z); a6 += bf_lo(u7.w); a7 += bf_hi(u7.w); }
    }
    // merge the 4 edge-slots: xor 8,16 stay within the 32-lane node half, sub preserved
    a0 += __shfl_xor(a0, 8, 64); a0 += __shfl_xor(a0, 16, 64);
    a1 += __shfl_xor(a1, 8, 64); a1 += __shfl_xor(a1, 16, 64);
    a2 += __shfl_xor(a2, 8, 64); a2 += __shfl_xor(a2, 16, 64);
    a3 += __shfl_xor(a3, 8, 64); a3 += __shfl_xor(a3, 16, 64);
    a4 += __shfl_xor(a4, 8, 64); a4 += __shfl_xor(a4, 16, 64);
    a5 += __shfl_xor(a5, 8, 64); a5 += __shfl_xor(a5, 16, 64);
    a6 += __shfl_xor(a6, 8, 64); a6 += __shfl_xor(a6, 16, 64);
    a7 += __shfl_xor(a7, 8, 64); a7 += __shfl_xor(a7, 16, 64);
    if (grp == 0) {
        a0 += bf_lo(su.x); a1 += bf_hi(su.x); a2 += bf_lo(su.y); a3 += bf_hi(su.y);  // self-loop
        a4 += bf_lo(su.z); a5 += bf_hi(su.z); a6 += bf_lo(su.w); a7 += bf_hi(su.w);
        const float4* b4 = (const float4*)bias;
        float4 bv0 = b4[2 * sub], bv1 = b4[2 * sub + 1];
        float4* o4 = (float4*)&out[(size_t)node * CH + 8 * sub];
        o4[0] = make_float4(d * a0 + bv0.x, d * a1 + bv0.y, d * a2 + bv0.z, d * a3 + bv0.w);
        o4[1] = make_float4(d * a4 + bv1.x, d * a5 + bv1.y, d * a6 + bv1.z, d * a7 + bv1.w);
    }
}

extern "C" void kernel_launch(void* const* d_in, const int* in_sizes, int n_in,
                              void* d_out, int out_size, void* d_ws, size_t ws_size,
                              hipStream_t stream) {
    const float* x  = (const float*)d_in[0];
    const int*   ei = (const int*)d_in[1];  // [2, M] flat int32
    const float* W  = (const float*)d_in[2];
    const float* bv = (const float*)d_in[3];
    float* out = (float*)d_out;

    const int* row = ei;
    const int* col = ei + M_EDGES;

    // workspace layout (~22.4 MB; every byte read is written first -> no memset needed):
    char* ws = (char*)d_ws;
    int*          bbase = (int*)(ws + 0);                    // (NB+1)*4 = 3,132 B
    int*          bcur  = (int*)(ws + (8 << 10));            // NB*4 = 3,128 B
    float*        dis   = (float*)(ws + (512 << 10));        // 400,000 B
    int*          nstart= (int*)(ws + (1024 << 10));         // 400,004 B (N+1, sentinel)
    int*          T     = (int*)(ws + (1536 << 10));         // 196*782*4 = 613,088 B (ends ~2.1 MB)
    unsigned int* g2    = (unsigned int*)(ws + (3u << 20));  // 12,800,000 B bf16 g (3 .. 15.8 MB)
    unsigned int* pairs = (unsigned int*)(ws + (16u << 20)); // 6,400,000 B (16 .. 22.4 MB)

    k_bhist<<<PART_BLOCKS, 256, 0, stream>>>(col, T);
    k_sumscan<<<1, 1024, 0, stream>>>(T, bbase, bcur);
    k_partition<<<PART_BLOCKS, 256, 0, stream>>>(row, col, bcur, T, pairs);
    k_fine<<<NB, 256, 0, stream>>>(bbase, pairs, nstart, dis);
    k_gemm_g<<<GBLKS, 256, 0, stream>>>(x, W, dis, g2);
    k_aggregate<<<(N_NODES + 7) / 8, 256, 0, stream>>>(nstart, (const int*)pairs, dis, g2, bv, out);
}

// Round 10
// 180.647 us; speedup vs baseline: 1.0955x; 1.0955x over previous
//
#include <hip/hip_runtime.h>

#define N_NODES 100000
#define M_EDGES 1600000
#define CH 64
#define NPB 128                              // nodes per bucket (col >> 7)
#define NB ((N_NODES + NPB - 1) / NPB)       // 782 buckets
#define CAP 3072                             // padded slots per bucket (mean 2046 + 22.6 sigma)
#define PART_CHUNK 8192
#define PART_BLOCKS ((M_EDGES + PART_CHUNK - 1) / PART_CHUNK)  // 196
#define REG_E 12                             // 256 thr * 12 = 3072 = CAP
#define GROWS 192                            // gemm rows per block
#define GBLKS ((N_NODES + GROWS - 1) / GROWS)  // 521

// f32 -> bf16 (RNE) pack of two channels into one uint
__device__ __forceinline__ unsigned int pack_bf16x2(float a, float b) {
    unsigned int ua = __float_as_uint(a);
    ua = (ua + 0x7fffu + ((ua >> 16) & 1u)) >> 16;
    unsigned int ub = __float_as_uint(b);
    ub = (ub + 0x7fffu + ((ub >> 16) & 1u)) >> 16;
    return ua | (ub << 16);
}
__device__ __forceinline__ float bf_lo(unsigned int u) { return __uint_as_float(u << 16); }
__device__ __forceinline__ float bf_hi(unsigned int u) { return __uint_as_float(u & 0xffff0000u); }

// ---------- partition into PADDED bucket regions: hist -> claim -> scatter ----------
// bucket b owns pairs[b*CAP .. b*CAP+count_b); blocks claim sub-ranges via bcur (memset 0).
__global__ __launch_bounds__(256) void k_partition(const int* __restrict__ row, const int* __restrict__ col,
                                                   int* __restrict__ bcur, unsigned int* __restrict__ pairs) {
    __shared__ int h[NB];
    int tid = threadIdx.x;
    int c = blockIdx.x;
    for (int i = tid; i < NB; i += 256) h[i] = 0;
    __syncthreads();
    const int4* c4 = (const int4*)col;
    const int4* r4 = (const int4*)row;
    int start4 = c * (PART_CHUNK / 4);
    int end4 = min(M_EDGES / 4, start4 + PART_CHUNK / 4);
    // pass 1: LDS histogram of this chunk
    for (int e = start4 + tid; e < end4; e += 256) {
        int4 v = c4[e];
        atomicAdd(&h[v.x >> 7], 1);
        atomicAdd(&h[v.y >> 7], 1);
        atomicAdd(&h[v.z >> 7], 1);
        atomicAdd(&h[v.w >> 7], 1);
    }
    __syncthreads();
    // claim contiguous sub-ranges within each bucket's padded region
    for (int i = tid; i < NB; i += 256) {
        int cnt = h[i];
        h[i] = cnt ? (i * CAP + atomicAdd(&bcur[i], cnt)) : 0;
    }
    __syncthreads();
    // pass 2: scatter packed (row<<7 | col&127); chunk data is L2-resident from pass 1
    for (int e = start4 + tid; e < end4; e += 256) {
        int4 cc = c4[e];
        int4 rr = r4[e];
        int pos;
        pos = atomicAdd(&h[cc.x >> 7], 1);
        pairs[pos] = ((unsigned int)rr.x << 7) | (unsigned int)(cc.x & 127);
        pos = atomicAdd(&h[cc.y >> 7], 1);
        pairs[pos] = ((unsigned int)rr.y << 7) | (unsigned int)(cc.y & 127);
        pos = atomicAdd(&h[cc.z >> 7], 1);
        pairs[pos] = ((unsigned int)rr.z << 7) | (unsigned int)(cc.z & 127);
        pos = atomicAdd(&h[cc.w >> 7], 1);
        pairs[pos] = ((unsigned int)rr.w << 7) | (unsigned int)(cc.w & 127);
    }
}

// ---------- in-place per-bucket counting sort; emits nstart, nend, dis ----------
__global__ __launch_bounds__(256) void k_fine(const int* __restrict__ bcur,
                                              unsigned int* __restrict__ pairs, int* __restrict__ nstart,
                                              int* __restrict__ nend, float* __restrict__ dis) {
    __shared__ int lcnt[NPB];
    __shared__ int lcur[NPB];
    __shared__ int ss[NPB];
    int b = blockIdx.x, t = threadIdx.x;
    int s0 = b * CAP;
    int e0 = s0 + bcur[b];  // bucket count after partition

    if (t < NPB) lcnt[t] = 0;
    __syncthreads();

    unsigned int reg[REG_E];  // compile-time indexed only (rule #20)
#pragma unroll
    for (int k = 0; k < REG_E; k++) {
        int e = s0 + t + k * 256;
        if (e < e0) {
            unsigned int p = pairs[e];
            reg[k] = p;
            atomicAdd(&lcnt[p & 127u], 1);
        }
    }
    __syncthreads();

    int v = 0;
    if (t < NPB) { v = lcnt[t]; ss[t] = v; }
    __syncthreads();
    for (int off = 1; off < NPB; off <<= 1) {
        int tv = (t < NPB && t >= off) ? ss[t - off] : 0;
        __syncthreads();
        if (t < NPB) ss[t] += tv;
        __syncthreads();
    }
    if (t < NPB) {
        int excl = ss[t] - v;
        lcur[t] = excl;
        int node = b * NPB + t;
        if (node < N_NODES) {
            nstart[node] = s0 + excl;
            nend[node] = s0 + excl + v;
            dis[node] = 1.0f / sqrtf((float)(v + 1));  // degree incl. self-loop
        }
    }
    __syncthreads();

#pragma unroll
    for (int k = 0; k < REG_E; k++) {
        int e = s0 + t + k * 256;
        if (e < e0) {
            unsigned int p = reg[k];
            int pos = atomicAdd(&lcur[p & 127u], 1);
            pairs[s0 + pos] = p >> 7;  // rows grouped by target node
        }
    }
}

// ---------- g = dis[r] * (x @ W), packed bf16; wave = 16-col quad, lane = row, 3 rows/thread ----------
__global__ __launch_bounds__(256) void k_gemm_g(const float* __restrict__ x, const float* __restrict__ W,
                                                const float* __restrict__ dis, unsigned int* __restrict__ g2) {
    __shared__ float sW[64][64];
    __shared__ float sXf[GROWS * 65];  // [row][k] with +1 pad
    int t = threadIdx.x;
    int row0 = blockIdx.x * GROWS;
    int nrows = min(GROWS, N_NODES - row0);

    for (int i = t; i < 64 * 64; i += 256) sW[i >> 6][i & 63] = W[i];
    const float4* xv = (const float4*)x;
    for (int idx = t; idx < GROWS * 16; idx += 256) {
        int r = idx >> 4, c4 = idx & 15;
        float4 v = (r < nrows) ? xv[(size_t)(row0 + r) * 16 + c4] : make_float4(0.f, 0.f, 0.f, 0.f);
        sXf[r * 65 + c4 * 4 + 0] = v.x;
        sXf[r * 65 + c4 * 4 + 1] = v.y;
        sXf[r * 65 + c4 * 4 + 2] = v.z;
        sXf[r * 65 + c4 * 4 + 3] = v.w;
    }
    __syncthreads();

    int q = t >> 6;          // wave id -> col quad
    int rid = t & 63;        // lane -> row
    int c0 = q * 16;
    float acc0[16], acc1[16], acc2[16];
#pragma unroll
    for (int j = 0; j < 16; j++) { acc0[j] = 0.f; acc1[j] = 0.f; acc2[j] = 0.f; }

    for (int k = 0; k < 64; k++) {
        float xv0 = sXf[rid * 65 + k];
        float xv1 = sXf[(rid + 64) * 65 + k];
        float xv2 = sXf[(rid + 128) * 65 + k];
        const float4* wp = (const float4*)&sW[k][c0];  // same addr across wave: broadcast
        float4 w0 = wp[0], w1 = wp[1], w2 = wp[2], w3 = wp[3];
        float wv[16] = {w0.x, w0.y, w0.z, w0.w, w1.x, w1.y, w1.z, w1.w,
                        w2.x, w2.y, w2.z, w2.w, w3.x, w3.y, w3.z, w3.w};
#pragma unroll
        for (int j = 0; j < 16; j++) {
            acc0[j] += xv0 * wv[j];
            acc1[j] += xv1 * wv[j];
            acc2[j] += xv2 * wv[j];
        }
    }

#pragma unroll
    for (int jr = 0; jr < 3; jr++) {
        int r = rid + jr * 64;
        int gr = row0 + r;
        if (r < nrows) {
            float* accp = (jr == 0) ? acc0 : (jr == 1) ? acc1 : acc2;  // unrolled: compile-time
            float d = dis[gr];
            uint4 wlo, whi;
            wlo.x = pack_bf16x2(d * accp[0], d * accp[1]);
            wlo.y = pack_bf16x2(d * accp[2], d * accp[3]);
            wlo.z = pack_bf16x2(d * accp[4], d * accp[5]);
            wlo.w = pack_bf16x2(d * accp[6], d * accp[7]);
            whi.x = pack_bf16x2(d * accp[8], d * accp[9]);
            whi.y = pack_bf16x2(d * accp[10], d * accp[11]);
            whi.z = pack_bf16x2(d * accp[12], d * accp[13]);
            whi.w = pack_bf16x2(d * accp[14], d * accp[15]);
            unsigned int base = (unsigned int)gr * 32 + q * 8;
            *reinterpret_cast<uint4*>(&g2[base]) = wlo;
            *reinterpret_cast<uint4*>(&g2[base + 4]) = whi;
        }
    }
}

// ---------- aggregation: 2 nodes/wave, 8 lanes/edge (uint4 = 8 ch), 16 edges/node/iter, MLP=4 ----------
// out[c] = dis[c] * (sum_e g[srow_e] + g[c]) + b     (round-8 proven version, nend instead of sentinel)
__global__ __launch_bounds__(256) void k_aggregate(const int* __restrict__ nstart, const int* __restrict__ nend,
                                                   const int* __restrict__ srow, const float* __restrict__ dis,
                                                   const unsigned int* __restrict__ g2,
                                                   const float* __restrict__ bias, float* __restrict__ out) {
    int node = blockIdx.x * 8 + (threadIdx.x >> 5);   // 32 lanes per node
    if (node >= N_NODES) return;
    int l = threadIdx.x & 31;
    int grp = l >> 3;   // edge slot 0..3
    int sub = l & 7;    // channel octet: channels 8*sub .. 8*sub+7
    const uint4* gq = (const uint4*)g2;  // one g-row = 8 uint4
    int s0 = nstart[node];
    int e0 = nend[node];
    float a0 = 0.f, a1 = 0.f, a2 = 0.f, a3 = 0.f, a4 = 0.f, a5 = 0.f, a6 = 0.f, a7 = 0.f;
    int e0m1 = e0 - 1;
    for (int i = s0; i < e0; i += 16) {  // masked 16-wide iters, MLP=4
        int ea = i + grp, eb = i + 4 + grp, ec = i + 8 + grp, ed = i + 12 + grp;
        int r0 = srow[min(ea, e0m1)];
        int r1 = srow[min(eb, e0m1)];
        int r2 = srow[min(ec, e0m1)];
        int r3 = srow[min(ed, e0m1)];
        uint4 u0 = gq[(unsigned int)r0 * 8 + sub];
        uint4 u1 = gq[(unsigned int)r1 * 8 + sub];
        uint4 u2 = gq[(unsigned int)r2 * 8 + sub];
        uint4 u3 = gq[(unsigned int)r3 * 8 + sub];
        if (ea < e0) { a0 += bf_lo(u0.x); a1 += bf_hi(u0.x); a2 += bf_lo(u0.y); a3 += bf_hi(u0.y);
                       a4 += bf_lo(u0.z); a5 += bf_hi(u0.z); a6 += bf_lo(u0.w); a7 += bf_hi(u0.w); }
        if (eb < e0) { a0 += bf_lo(u1.x); a1 += bf_hi(u1.x); a2 += bf_lo(u1.y); a3 += bf_hi(u1.y);
                       a4 += bf_lo(u1.z); a5 += bf_hi(u1.z); a6 += bf_lo(u1.w); a7 += bf_hi(u1.w); }
        if (ec < e0) { a0 += bf_lo(u2.x); a1 += bf_hi(u2.x); a2 += bf_lo(u2.y); a3 += bf_hi(u2.y);
                       a4 += bf_lo(u2.z); a5 += bf_hi(u2.z); a6 += bf_lo(u2.w); a7 += bf_hi(u2.w); }
        if (ed < e0) { a0 += bf_lo(u3.x); a1 += bf_hi(u3.x); a2 += bf_lo(u3.y); a3 += bf_hi(u3.y);
                       a4 += bf_lo(u3.z); a5 += bf_hi(u3.z); a6 += bf_lo(u3.w); a7 += bf_hi(u3.w); }
    }
    // merge the 4 edge-slots: xor 8,16 stay within the 32-lane node half, sub preserved
    a0 += __shfl_xor(a0, 8, 64); a0 += __shfl_xor(a0, 16, 64);
    a1 += __shfl_xor(a1, 8, 64); a1 += __shfl_xor(a1, 16, 64);
    a2 += __shfl_xor(a2, 8, 64); a2 += __shfl_xor(a2, 16, 64);
    a3 += __shfl_xor(a3, 8, 64); a3 += __shfl_xor(a3, 16, 64);
    a4 += __shfl_xor(a4, 8, 64); a4 += __shfl_xor(a4, 16, 64);
    a5 += __shfl_xor(a5, 8, 64); a5 += __shfl_xor(a5, 16, 64);
    a6 += __shfl_xor(a6, 8, 64); a6 += __shfl_xor(a6, 16, 64);
    a7 += __shfl_xor(a7, 8, 64); a7 += __shfl_xor(a7, 16, 64);
    if (grp == 0) {
        uint4 su = gq[(unsigned int)node * 8 + sub];  // self-loop term
        a0 += bf_lo(su.x); a1 += bf_hi(su.x); a2 += bf_lo(su.y); a3 += bf_hi(su.y);
        a4 += bf_lo(su.z); a5 += bf_hi(su.z); a6 += bf_lo(su.w); a7 += bf_hi(su.w);
        float d = dis[node];
        const float4* b4 = (const float4*)bias;
        float4 bv0 = b4[2 * sub], bv1 = b4[2 * sub + 1];
        float4* o4 = (float4*)&out[(size_t)node * CH + 8 * sub];
        o4[0] = make_float4(d * a0 + bv0.x, d * a1 + bv0.y, d * a2 + bv0.z, d * a3 + bv0.w);
        o4[1] = make_float4(d * a4 + bv1.x, d * a5 + bv1.y, d * a6 + bv1.z, d * a7 + bv1.w);
    }
}

extern "C" void kernel_launch(void* const* d_in, const int* in_sizes, int n_in,
                              void* d_out, int out_size, void* d_ws, size_t ws_size,
                              hipStream_t stream) {
    const float* x  = (const float*)d_in[0];
    const int*   ei = (const int*)d_in[1];  // [2, M] flat int32
    const float* W  = (const float*)d_in[2];
    const float* bv = (const float*)d_in[3];
    float* out = (float*)d_out;

    const int* row = ei;
    const int* col = ei + M_EDGES;

    // workspace layout (~25.6 MB):
    char* ws = (char*)d_ws;
    int*          bcur  = (int*)(ws + 0);                    // NB*4 = 3,128 B (memset 0)
    float*        dis   = (float*)(ws + (512 << 10));        // 400,000 B
    int*          nstart= (int*)(ws + (1024 << 10));         // 400,000 B
    int*          nend  = (int*)(ws + (1536 << 10));         // 400,000 B
    unsigned int* g2    = (unsigned int*)(ws + (3u << 20));  // 12,800,000 B bf16 g (3 .. 15.8 MB)
    unsigned int* pairs = (unsigned int*)(ws + (16u << 20)); // NB*CAP*4 = 9,609,216 B (16 .. 25.6 MB)

    hipMemsetAsync(bcur, 0, NB * sizeof(int), stream);

    k_partition<<<PART_BLOCKS, 256, 0, stream>>>(row, col, bcur, pairs);
    k_fine<<<NB, 256, 0, stream>>>(bcur, pairs, nstart, nend, dis);
    k_gemm_g<<<GBLKS, 256, 0, stream>>>(x, W, dis, g2);
    k_aggregate<<<(N_NODES + 7) / 8, 256, 0, stream>>>(nstart, nend, (const int*)pairs, dis, g2, bv, out);
}